// Round 14
// baseline (457.196 us; speedup 1.0000x reference)
//
#include <hip/hip_runtime.h>
#include <hip/hip_bf16.h>

#define NN 50000
#define EE 800000
#define NB 196   // ceil(NN/256)

typedef short short8 __attribute__((ext_vector_type(8)));
typedef float f32x4 __attribute__((ext_vector_type(4)));

__device__ __forceinline__ float lrelu(float x) { return x > 0.f ? x : 0.2f * x; }

__device__ __forceinline__ unsigned short f2bf(float x) {
    __hip_bfloat16 b = __float2bfloat16(x);
    return *(unsigned short*)&b;
}
__device__ __forceinline__ float bf2f(unsigned short u) {
    return __uint_as_float(((unsigned int)u) << 16);
}

// ---------------- CSR build ----------------
__global__ void hist_k(const int* __restrict__ dst, int* __restrict__ deg) {
    int i = blockIdx.x * 256 + threadIdx.x;
    if (i < EE) atomicAdd(&deg[dst[i]], 1);
}

__global__ __launch_bounds__(256) void scanA_k(const int* __restrict__ deg,
                                               int* __restrict__ cscan,
                                               int* __restrict__ bsum) {
    __shared__ int wtot[4];
    int tid = threadIdx.x, lane = tid & 63, w = tid >> 6;
    int i = blockIdx.x * 256 + tid;
    int v = (i < NN) ? deg[i] : 0;
    int x = v;
#pragma unroll
    for (int off = 1; off < 64; off <<= 1) {
        int y = __shfl_up(x, off);
        if (lane >= off) x += y;
    }
    if (lane == 63) wtot[w] = x;
    __syncthreads();
    int prefix = 0;
#pragma unroll
    for (int j = 0; j < 4; ++j)
        if (j < w) prefix += wtot[j];
    x += prefix;
    if (i < NN) cscan[i] = x;
    if (tid == 255) bsum[blockIdx.x] = x;
}

__global__ __launch_bounds__(256) void scanB_k(const int* __restrict__ bsum,
                                               int* __restrict__ boff) {
    __shared__ int wtot[4];
    int tid = threadIdx.x, lane = tid & 63, w = tid >> 6;
    int v = (tid < NB) ? bsum[tid] : 0;
    int x = v;
#pragma unroll
    for (int off = 1; off < 64; off <<= 1) {
        int y = __shfl_up(x, off);
        if (lane >= off) x += y;
    }
    if (lane == 63) wtot[w] = x;
    __syncthreads();
    int prefix = 0;
#pragma unroll
    for (int j = 0; j < 4; ++j)
        if (j < w) prefix += wtot[j];
    x += prefix;
    if (tid < NB) boff[tid] = x - v;
    if (tid == NB - 1) boff[NB] = x;
}

__global__ __launch_bounds__(256) void scanC_k(const int* __restrict__ deg,
                                               const int* __restrict__ cscan,
                                               const int* __restrict__ boff,
                                               int* __restrict__ row_ptr,
                                               int* __restrict__ cursor) {
    int i = blockIdx.x * 256 + threadIdx.x;
    if (i < NN) {
        int e = boff[i >> 8] + cscan[i] - deg[i];
        row_ptr[i] = e;
        cursor[i] = e;
    }
    if (i == 0) row_ptr[NN] = boff[NB];
}

__global__ void scatter_k(const int* __restrict__ src, const int* __restrict__ dst,
                          int* __restrict__ cursor, int* __restrict__ csr_src) {
    int i = blockIdx.x * 256 + threadIdx.x;
    if (i < EE) {
        int slot = atomicAdd(&cursor[dst[i]], 1);
        csr_src[slot] = src[i];
    }
}

// ---------------- weights -> bf16 ----------------
__global__ __launch_bounds__(256) void bconv_k(const float* __restrict__ W2,
                                               const float* __restrict__ W3,
                                               const float* __restrict__ mW1,
                                               unsigned short* __restrict__ BT2,
                                               unsigned short* __restrict__ BT3,
                                               unsigned short* __restrict__ W1Tb) {
    int tid = blockIdx.x * 256 + threadIdx.x;   // 65536
    int k = tid & 255, n = tid >> 8;
    BT2[n * 256 + k] = f2bf(W2[k * 256 + n]);
    BT3[n * 256 + k] = f2bf(W3[k * 256 + n]);
    if (tid < 4096) {
        int kk = tid & 63, nn = tid >> 6;
        W1Tb[nn * 64 + kk] = f2bf(mW1[kk * 64 + nn]);
    }
}

// ---------------- layer-1 attention logits (pos-based) ----------------
__global__ __launch_bounds__(256) void eler1_k(const float* __restrict__ pos,
                                               const float* __restrict__ W1,
                                               const float* __restrict__ al,
                                               const float* __restrict__ ar,
                                               float* __restrict__ el,
                                               float* __restrict__ er) {
    int wid = blockIdx.x * 4 + (threadIdx.x >> 6);
    int lane = threadIdx.x & 63;
    if (wid >= NN) return;
    int f = lane * 4;
    float4 w0 = *(const float4*)&W1[f];
    float4 w1 = *(const float4*)&W1[256 + f];
    float4 a4 = *(const float4*)&al[f];
    float4 r4 = *(const float4*)&ar[f];
    float2 p = *(const float2*)&pos[wid * 2];
    float fx = p.x * w0.x + p.y * w1.x;
    float fy = p.x * w0.y + p.y * w1.y;
    float fz = p.x * w0.z + p.y * w1.z;
    float fw = p.x * w0.w + p.y * w1.w;
    float pl = fx * a4.x + fy * a4.y + fz * a4.z + fw * a4.w;
    float pr = fx * r4.x + fy * r4.y + fz * r4.z + fw * r4.w;
#pragma unroll
    for (int off = 1; off < 16; off <<= 1) {
        pl += __shfl_xor(pl, off);
        pr += __shfl_xor(pr, off);
    }
    if ((lane & 15) == 0) {
        int h = lane >> 4;
        el[wid * 4 + h] = pl;
        er[wid * 4 + h] = pr;
    }
}

// ---------------- layer-1 aggregation: wave-parallel edges (16 lanes per head) ----------------
__global__ __launch_bounds__(256) void agg1_k(const float* __restrict__ pos,
                                              const float* __restrict__ W1,
                                              const float* __restrict__ resW1,
                                              const float* __restrict__ el,
                                              const float* __restrict__ er,
                                              const int* __restrict__ row_ptr,
                                              const int* __restrict__ csr_src,
                                              unsigned short* __restrict__ hb16) {
    int wid = blockIdx.x * 4 + (threadIdx.x >> 6);
    int lane = threadIdx.x & 63;
    if (wid >= NN) return;
    int f = lane * 4;
    int start = row_ptr[wid], end = row_ptr[wid + 1];
    int h = lane >> 4, sub = lane & 15;
    float eh = er[wid * 4 + h];

    float ap0 = 0.f, ap1 = 0.f, den = 0.f;
    for (int s = start + sub; s < end; s += 16) {
        int sn = csr_src[s];
        float w = __expf(lrelu(el[sn * 4 + h] + eh));
        float2 p = *(const float2*)&pos[sn * 2];
        den += w;
        ap0 += w * p.x;
        ap1 += w * p.y;
    }
#pragma unroll
    for (int off = 1; off < 16; off <<= 1) {
        den += __shfl_xor(den, off);
        ap0 += __shfl_xor(ap0, off);
        ap1 += __shfl_xor(ap1, off);
    }
    float inv = 1.f / fmaxf(den, 1e-9f);
    ap0 *= inv;
    ap1 *= inv;

    float4 w0 = *(const float4*)&W1[f];
    float4 w1 = *(const float4*)&W1[256 + f];
    float4 rw0 = *(const float4*)&resW1[f];
    float4 rw1 = *(const float4*)&resW1[256 + f];
    float2 pd = *(const float2*)&pos[wid * 2];
    float4 o;
    o.x = fmaxf(ap0 * w0.x + ap1 * w1.x + pd.x * rw0.x + pd.y * rw1.x, 0.f);
    o.y = fmaxf(ap0 * w0.y + ap1 * w1.y + pd.x * rw0.y + pd.y * rw1.y, 0.f);
    o.z = fmaxf(ap0 * w0.z + ap1 * w1.z + pd.x * rw0.z + pd.y * rw1.z, 0.f);
    o.w = fmaxf(ap0 * w0.w + ap1 * w1.w + pd.x * rw0.w + pd.y * rw1.w, 0.f);
    ushort4 ob;
    ob.x = f2bf(o.x); ob.y = f2bf(o.y); ob.z = f2bf(o.z); ob.w = f2bf(o.w);
    *(ushort4*)&hb16[(size_t)wid * 256 + f] = ob;
}

// ---------------- layer-2 aggregation: one-pass softmax, unroll-4 ----------------
__global__ __launch_bounds__(256) void agg_k(const unsigned short* __restrict__ featb,
                                             const float* __restrict__ el,
                                             const float* __restrict__ er,
                                             const int* __restrict__ row_ptr,
                                             const int* __restrict__ csr_src,
                                             unsigned short* __restrict__ hb16) {
    int wid = blockIdx.x * 4 + (threadIdx.x >> 6);
    int lane = threadIdx.x & 63;
    if (wid >= NN) return;
    int f = lane * 4;
    int start = row_ptr[wid], end = row_ptr[wid + 1];
    int h = lane >> 4;
    float eh = er[wid * 4 + h];

    float4 acc = {0.f, 0.f, 0.f, 0.f};
    float den = 0.f;
    int s = start;
    for (; s + 3 < end; s += 4) {
        int sn0 = csr_src[s], sn1 = csr_src[s + 1];
        int sn2 = csr_src[s + 2], sn3 = csr_src[s + 3];
        float e0 = el[sn0 * 4 + h], e1 = el[sn1 * 4 + h];
        float e2 = el[sn2 * 4 + h], e3 = el[sn3 * 4 + h];
        ushort4 v0 = *(const ushort4*)&featb[(size_t)sn0 * 256 + f];
        ushort4 v1 = *(const ushort4*)&featb[(size_t)sn1 * 256 + f];
        ushort4 v2 = *(const ushort4*)&featb[(size_t)sn2 * 256 + f];
        ushort4 v3 = *(const ushort4*)&featb[(size_t)sn3 * 256 + f];
        float w0 = __expf(lrelu(e0 + eh)), w1 = __expf(lrelu(e1 + eh));
        float w2 = __expf(lrelu(e2 + eh)), w3 = __expf(lrelu(e3 + eh));
        den += (w0 + w1) + (w2 + w3);
        acc.x += w0 * bf2f(v0.x) + w1 * bf2f(v1.x) + w2 * bf2f(v2.x) + w3 * bf2f(v3.x);
        acc.y += w0 * bf2f(v0.y) + w1 * bf2f(v1.y) + w2 * bf2f(v2.y) + w3 * bf2f(v3.y);
        acc.z += w0 * bf2f(v0.z) + w1 * bf2f(v1.z) + w2 * bf2f(v2.z) + w3 * bf2f(v3.z);
        acc.w += w0 * bf2f(v0.w) + w1 * bf2f(v1.w) + w2 * bf2f(v2.w) + w3 * bf2f(v3.w);
    }
    for (; s < end; ++s) {
        int sn = csr_src[s];
        float w = __expf(lrelu(el[sn * 4 + h] + eh));
        ushort4 v = *(const ushort4*)&featb[(size_t)sn * 256 + f];
        den += w;
        acc.x += w * bf2f(v.x);
        acc.y += w * bf2f(v.y);
        acc.z += w * bf2f(v.z);
        acc.w += w * bf2f(v.w);
    }
    float inv = 1.f / fmaxf(den, 1e-9f);
    ushort4 rb = *(const ushort4*)&hb16[(size_t)wid * 256 + f];
    float4 o;
    o.x = fmaxf(acc.x * inv + bf2f(rb.x), 0.f);
    o.y = fmaxf(acc.y * inv + bf2f(rb.y), 0.f);
    o.z = fmaxf(acc.z * inv + bf2f(rb.z), 0.f);
    o.w = fmaxf(acc.w * inv + bf2f(rb.w), 0.f);
    ushort4 ob;
    ob.x = f2bf(o.x); ob.y = f2bf(o.y); ob.z = f2bf(o.z); ob.w = f2bf(o.w);
    *(ushort4*)&hb16[(size_t)wid * 256 + f] = ob;
}

// ---------------- layer-3 aggregation, mean over heads -> bf16 hsmall ----------------
__global__ __launch_bounds__(256) void agg3_k(const unsigned short* __restrict__ featb,
                                              const float* __restrict__ el,
                                              const float* __restrict__ er,
                                              const int* __restrict__ row_ptr,
                                              const int* __restrict__ csr_src,
                                              const unsigned short* __restrict__ hresb,
                                              unsigned short* __restrict__ hsmallb) {
    int wid = blockIdx.x * 4 + (threadIdx.x >> 6);
    int lane = threadIdx.x & 63;
    if (wid >= NN) return;
    int f = lane * 4;
    int start = row_ptr[wid], end = row_ptr[wid + 1];
    int h = lane >> 4;
    float eh = er[wid * 4 + h];

    float4 acc = {0.f, 0.f, 0.f, 0.f};
    float den = 0.f;
    int s = start;
    for (; s + 3 < end; s += 4) {
        int sn0 = csr_src[s], sn1 = csr_src[s + 1];
        int sn2 = csr_src[s + 2], sn3 = csr_src[s + 3];
        float e0 = el[sn0 * 4 + h], e1 = el[sn1 * 4 + h];
        float e2 = el[sn2 * 4 + h], e3 = el[sn3 * 4 + h];
        ushort4 v0 = *(const ushort4*)&featb[(size_t)sn0 * 256 + f];
        ushort4 v1 = *(const ushort4*)&featb[(size_t)sn1 * 256 + f];
        ushort4 v2 = *(const ushort4*)&featb[(size_t)sn2 * 256 + f];
        ushort4 v3 = *(const ushort4*)&featb[(size_t)sn3 * 256 + f];
        float w0 = __expf(lrelu(e0 + eh)), w1 = __expf(lrelu(e1 + eh));
        float w2 = __expf(lrelu(e2 + eh)), w3 = __expf(lrelu(e3 + eh));
        den += (w0 + w1) + (w2 + w3);
        acc.x += w0 * bf2f(v0.x) + w1 * bf2f(v1.x) + w2 * bf2f(v2.x) + w3 * bf2f(v3.x);
        acc.y += w0 * bf2f(v0.y) + w1 * bf2f(v1.y) + w2 * bf2f(v2.y) + w3 * bf2f(v3.y);
        acc.z += w0 * bf2f(v0.z) + w1 * bf2f(v1.z) + w2 * bf2f(v2.z) + w3 * bf2f(v3.z);
        acc.w += w0 * bf2f(v0.w) + w1 * bf2f(v1.w) + w2 * bf2f(v2.w) + w3 * bf2f(v3.w);
    }
    for (; s < end; ++s) {
        int sn = csr_src[s];
        float w = __expf(lrelu(el[sn * 4 + h] + eh));
        ushort4 v = *(const ushort4*)&featb[(size_t)sn * 256 + f];
        den += w;
        acc.x += w * bf2f(v.x);
        acc.y += w * bf2f(v.y);
        acc.z += w * bf2f(v.z);
        acc.w += w * bf2f(v.w);
    }
    float inv = 1.f / fmaxf(den, 1e-9f);
    ushort4 rb = *(const ushort4*)&hresb[(size_t)wid * 256 + f];
    float4 o;
    o.x = acc.x * inv + bf2f(rb.x);
    o.y = acc.y * inv + bf2f(rb.y);
    o.z = acc.z * inv + bf2f(rb.z);
    o.w = acc.w * inv + bf2f(rb.w);
    o.x += __shfl_xor(o.x, 16); o.y += __shfl_xor(o.y, 16);
    o.z += __shfl_xor(o.z, 16); o.w += __shfl_xor(o.w, 16);
    o.x += __shfl_xor(o.x, 32); o.y += __shfl_xor(o.y, 32);
    o.z += __shfl_xor(o.z, 32); o.w += __shfl_xor(o.w, 32);
    if (lane < 16) {
        ushort4 m4;
        m4.x = f2bf(o.x * 0.25f);
        m4.y = f2bf(o.y * 0.25f);
        m4.z = f2bf(o.z * 0.25f);
        m4.w = f2bf(o.w * 0.25f);
        *(ushort4*)&hsmallb[(size_t)wid * 64 + lane * 4] = m4;
    }
}

// ---------------- MFMA GEMM (LDS-staged) + fused el/er epilogue ----------------
__global__ __launch_bounds__(256) void gemm_mfma_k(const unsigned short* __restrict__ Ab,
                                                   const unsigned short* __restrict__ BT,
                                                   const float* __restrict__ al,
                                                   const float* __restrict__ ar,
                                                   unsigned short* __restrict__ C,
                                                   float* __restrict__ el,
                                                   float* __restrict__ er) {
    __shared__ __align__(16) short As[128 * 40];
    __shared__ __align__(16) short Bs[128 * 40];
    int tid = threadIdx.x;
    int lane = tid & 63, wave = tid >> 6;
    int wr = wave >> 1, wc = wave & 1;
    int tileM = blockIdx.x * 128;
    int tileN = blockIdx.y * 128;

    int srow = tid >> 1, sko = (tid & 1) * 16;
    int fm = lane & 15, kg = lane >> 4;

    f32x4 acc[4][4];
#pragma unroll
    for (int i = 0; i < 4; ++i)
#pragma unroll
        for (int j = 0; j < 4; ++j) acc[i][j] = (f32x4){0.f, 0.f, 0.f, 0.f};

    for (int k0 = 0; k0 < 256; k0 += 32) {
        int gr = tileM + srow;
        short8 a0 = (short8)0, a1 = (short8)0;
        if (gr < NN) {
            a0 = *(const short8*)&Ab[(size_t)gr * 256 + k0 + sko];
            a1 = *(const short8*)&Ab[(size_t)gr * 256 + k0 + sko + 8];
        }
        *(short8*)&As[srow * 40 + sko] = a0;
        *(short8*)&As[srow * 40 + sko + 8] = a1;
        short8 b0 = *(const short8*)&BT[(size_t)(tileN + srow) * 256 + k0 + sko];
        short8 b1 = *(const short8*)&BT[(size_t)(tileN + srow) * 256 + k0 + sko + 8];
        *(short8*)&Bs[srow * 40 + sko] = b0;
        *(short8*)&Bs[srow * 40 + sko + 8] = b1;
        __syncthreads();

        short8 afr[4], bfr[4];
#pragma unroll
        for (int mi = 0; mi < 4; ++mi)
            afr[mi] = *(const short8*)&As[(wr * 64 + mi * 16 + fm) * 40 + kg * 8];
#pragma unroll
        for (int ni = 0; ni < 4; ++ni)
            bfr[ni] = *(const short8*)&Bs[(wc * 64 + ni * 16 + fm) * 40 + kg * 8];
#pragma unroll
        for (int mi = 0; mi < 4; ++mi)
#pragma unroll
            for (int ni = 0; ni < 4; ++ni)
                acc[mi][ni] = __builtin_amdgcn_mfma_f32_16x16x32_bf16(
                    afr[mi], bfr[ni], acc[mi][ni], 0, 0, 0);
        __syncthreads();
    }

#pragma unroll
    for (int mi = 0; mi < 4; ++mi) {
#pragma unroll
        for (int ni = 0; ni < 4; ++ni) {
            int col = tileN + wc * 64 + ni * 16 + fm;
#pragma unroll
            for (int r = 0; r < 4; ++r) {
                int row = tileM + wr * 64 + mi * 16 + kg * 4 + r;
                if (row < NN) C[(size_t)row * 256 + col] = f2bf(acc[mi][ni][r]);
            }
        }
    }

    int h = blockIdx.y * 2 + wc;
    float al_r[4], ar_r[4];
#pragma unroll
    for (int ni = 0; ni < 4; ++ni) {
        al_r[ni] = al[h * 64 + ni * 16 + fm];
        ar_r[ni] = ar[h * 64 + ni * 16 + fm];
    }
#pragma unroll
    for (int mi = 0; mi < 4; ++mi) {
#pragma unroll
        for (int r = 0; r < 4; ++r) {
            float tl = acc[mi][0][r] * al_r[0] + acc[mi][1][r] * al_r[1] +
                       acc[mi][2][r] * al_r[2] + acc[mi][3][r] * al_r[3];
            float tr = acc[mi][0][r] * ar_r[0] + acc[mi][1][r] * ar_r[1] +
                       acc[mi][2][r] * ar_r[2] + acc[mi][3][r] * ar_r[3];
#pragma unroll
            for (int off = 1; off < 16; off <<= 1) {
                tl += __shfl_xor(tl, off);
                tr += __shfl_xor(tr, off);
            }
            if (fm == 0) {
                int row = tileM + wr * 64 + mi * 16 + kg * 4 + r;
                if (row < NN) {
                    el[row * 4 + h] = tl;
                    er[row * 4 + h] = tr;
                }
            }
        }
    }
}

// ---------------- edge scoring MLP: MFMA, xs-only LDS (9.4KB), W1T fragments from global ----------------
__global__ __launch_bounds__(256) void edge_score4_k(const unsigned short* __restrict__ hs,
                                                     const int* __restrict__ src,
                                                     const int* __restrict__ dst,
                                                     const unsigned short* __restrict__ W1Tb,
                                                     const float* __restrict__ mb1,
                                                     const float* __restrict__ mW2,
                                                     const float* __restrict__ mb2,
                                                     float* __restrict__ out) {
    __shared__ __align__(16) unsigned short xs[64 * 72];
    int tid = threadIdx.x;
    int e_loc = tid >> 2, q = tid & 3;

    int e = blockIdx.x * 64 + e_loc;                 // EE % 64 == 0
    int s = src[e], d = dst[e];
    const unsigned short* rs = &hs[(size_t)s * 64 + q * 16];
    const unsigned short* rd = &hs[(size_t)d * 64 + q * 16];
    short8 a0 = *(const short8*)&rs[0];
    short8 a1 = *(const short8*)&rs[8];
    short8 b0 = *(const short8*)&rd[0];
    short8 b1 = *(const short8*)&rd[8];
    short8 x0, x1;
#pragma unroll
    for (int i = 0; i < 8; ++i) {
        x0[i] = (short)f2bf(fabsf(bf2f((unsigned short)a0[i]) - bf2f((unsigned short)b0[i])));
        x1[i] = (short)f2bf(fabsf(bf2f((unsigned short)a1[i]) - bf2f((unsigned short)b1[i])));
    }
    *(short8*)&xs[e_loc * 72 + q * 16]     = x0;
    *(short8*)&xs[e_loc * 72 + q * 16 + 8] = x1;
    __syncthreads();

    int lane = tid & 63, w = tid >> 6;
    int fm = lane & 15, kg = lane >> 4;

    const unsigned short* arow = &xs[(w * 16 + fm) * 72];
    short8 af0 = *(const short8*)&arow[kg * 8];
    short8 af1 = *(const short8*)&arow[32 + kg * 8];

    f32x4 acc[4];
#pragma unroll
    for (int ni = 0; ni < 4; ++ni) acc[ni] = (f32x4){0.f, 0.f, 0.f, 0.f};
#pragma unroll
    for (int ni = 0; ni < 4; ++ni) {
        const unsigned short* brow = &W1Tb[(ni * 16 + fm) * 64];
        short8 bf0 = *(const short8*)&brow[kg * 8];
        short8 bf1 = *(const short8*)&brow[32 + kg * 8];
        acc[ni] = __builtin_amdgcn_mfma_f32_16x16x32_bf16(af0, bf0, acc[ni], 0, 0, 0);
        acc[ni] = __builtin_amdgcn_mfma_f32_16x16x32_bf16(af1, bf1, acc[ni], 0, 0, 0);
    }

    float t0 = 0.f, t1 = 0.f, t2 = 0.f, t3 = 0.f;
#pragma unroll
    for (int ni = 0; ni < 4; ++ni) {
        int n = ni * 16 + fm;
        float bb = mb1[n], ww = mW2[n];
        t0 += fmaxf(acc[ni][0] + bb, 0.f) * ww;
        t1 += fmaxf(acc[ni][1] + bb, 0.f) * ww;
        t2 += fmaxf(acc[ni][2] + bb, 0.f) * ww;
        t3 += fmaxf(acc[ni][3] + bb, 0.f) * ww;
    }
#pragma unroll
    for (int off = 1; off < 16; off <<= 1) {
        t0 += __shfl_xor(t0, off);
        t1 += __shfl_xor(t1, off);
        t2 += __shfl_xor(t2, off);
        t3 += __shfl_xor(t3, off);
    }
    if (fm == 0) {
        float bias = mb2[0];
        int base = blockIdx.x * 64 + w * 16 + kg * 4;
        out[base + 0] = 1.f / (1.f + __expf(-(t0 + bias)));
        out[base + 1] = 1.f / (1.f + __expf(-(t1 + bias)));
        out[base + 2] = 1.f / (1.f + __expf(-(t2 + bias)));
        out[base + 3] = 1.f / (1.f + __expf(-(t3 + bias)));
    }
}

extern "C" void kernel_launch(void* const* d_in, const int* in_sizes, int n_in,
                              void* d_out, int out_size, void* d_ws, size_t ws_size,
                              hipStream_t stream) {
    (void)in_sizes; (void)n_in; (void)out_size; (void)ws_size;
    const float* pos   = (const float*)d_in[0];
    const int*   src   = (const int*)d_in[1];
    const int*   dst   = (const int*)d_in[2];
    const float* W1    = (const float*)d_in[3];
    const float* al1   = (const float*)d_in[4];
    const float* ar1   = (const float*)d_in[5];
    const float* resW1 = (const float*)d_in[6];
    const float* W2    = (const float*)d_in[7];
    const float* al2   = (const float*)d_in[8];
    const float* ar2   = (const float*)d_in[9];
    const float* W3    = (const float*)d_in[10];
    const float* al3   = (const float*)d_in[11];
    const float* ar3   = (const float*)d_in[12];
    const float* mW1   = (const float*)d_in[13];
    const float* mb1   = (const float*)d_in[14];
    const float* mW2   = (const float*)d_in[15];
    const float* mb2   = (const float*)d_in[16];
    float* out = (float*)d_out;

    char* ws = (char*)d_ws;
    size_t off = 0;
    auto alloc = [&](size_t bytes) {
        void* p = ws + off;
        off += (bytes + 255) & ~(size_t)255;
        return p;
    };
    unsigned short* FEATb  = (unsigned short*)alloc((size_t)NN * 256 * 2);
    unsigned short* Hb16   = (unsigned short*)alloc((size_t)NN * 256 * 2);
    unsigned short* BT2    = (unsigned short*)alloc((size_t)256 * 256 * 2);
    unsigned short* BT3    = (unsigned short*)alloc((size_t)256 * 256 * 2);
    unsigned short* W1Tb   = (unsigned short*)alloc((size_t)64 * 64 * 2);
    unsigned short* hsmallb = (unsigned short*)alloc((size_t)NN * 64 * 2);
    float* el     = (float*)alloc((size_t)NN * 4 * 4);
    float* er     = (float*)alloc((size_t)NN * 4 * 4);
    int* deg      = (int*)alloc((size_t)NN * 4);
    int* cscan    = (int*)alloc((size_t)NN * 4);
    int* bsum     = (int*)alloc((size_t)NB * 4);
    int* boff     = (int*)alloc((size_t)(NB + 1) * 4);
    int* row_ptr  = (int*)alloc((size_t)(NN + 1) * 4);
    int* cursor   = (int*)alloc((size_t)NN * 4);
    int* csr      = (int*)alloc((size_t)EE * 4);

    hipMemsetAsync(deg, 0, (size_t)NN * 4, stream);
    hist_k<<<(EE + 255) / 256, 256, 0, stream>>>(dst, deg);
    scanA_k<<<NB, 256, 0, stream>>>(deg, cscan, bsum);
    scanB_k<<<1, 256, 0, stream>>>(bsum, boff);
    scanC_k<<<NB, 256, 0, stream>>>(deg, cscan, boff, row_ptr, cursor);
    scatter_k<<<(EE + 255) / 256, 256, 0, stream>>>(src, dst, cursor, csr);
    bconv_k<<<256, 256, 0, stream>>>(W2, W3, mW1, BT2, BT3, W1Tb);

    // layer 1
    eler1_k<<<NN / 4 + 1, 256, 0, stream>>>(pos, W1, al1, ar1, el, er);
    agg1_k<<<NN / 4 + 1, 256, 0, stream>>>(pos, W1, resW1, el, er, row_ptr, csr, Hb16);

    dim3 ggrid((NN + 127) / 128, 2);
    // layer 2 (gemm computes FEATb + el/er in one pass)
    gemm_mfma_k<<<ggrid, 256, 0, stream>>>(Hb16, BT2, al2, ar2, FEATb, el, er);
    agg_k<<<NN / 4 + 1, 256, 0, stream>>>(FEATb, el, er, row_ptr, csr, Hb16);

    // layer 3
    gemm_mfma_k<<<ggrid, 256, 0, stream>>>(Hb16, BT3, al3, ar3, FEATb, el, er);
    agg3_k<<<NN / 4 + 1, 256, 0, stream>>>(FEATb, el, er, row_ptr, csr, Hb16, hsmallb);

    // edge MLP (MFMA)
    edge_score4_k<<<EE / 64, 256, 0, stream>>>(hsmallb, src, dst, W1Tb, mb1, mW2, mb2, out);
}

// Round 15
// 427.064 us; speedup vs baseline: 1.0706x; 1.0706x over previous
//
#include <hip/hip_runtime.h>
#include <hip/hip_bf16.h>

#define NN 50000
#define EE 800000
#define NB 196   // ceil(NN/256)

typedef short short8 __attribute__((ext_vector_type(8)));
typedef float f32x4 __attribute__((ext_vector_type(4)));

__device__ __forceinline__ float lrelu(float x) { return x > 0.f ? x : 0.2f * x; }

__device__ __forceinline__ unsigned short f2bf(float x) {
    __hip_bfloat16 b = __float2bfloat16(x);
    return *(unsigned short*)&b;
}
__device__ __forceinline__ float bf2f(unsigned short u) {
    return __uint_as_float(((unsigned int)u) << 16);
}

// ---------------- CSR build ----------------
__global__ void hist_k(const int* __restrict__ dst, int* __restrict__ deg) {
    int i = blockIdx.x * 256 + threadIdx.x;
    if (i < EE) atomicAdd(&deg[dst[i]], 1);
}

__global__ __launch_bounds__(256) void scanA_k(const int* __restrict__ deg,
                                               int* __restrict__ cscan,
                                               int* __restrict__ bsum) {
    __shared__ int wtot[4];
    int tid = threadIdx.x, lane = tid & 63, w = tid >> 6;
    int i = blockIdx.x * 256 + tid;
    int v = (i < NN) ? deg[i] : 0;
    int x = v;
#pragma unroll
    for (int off = 1; off < 64; off <<= 1) {
        int y = __shfl_up(x, off);
        if (lane >= off) x += y;
    }
    if (lane == 63) wtot[w] = x;
    __syncthreads();
    int prefix = 0;
#pragma unroll
    for (int j = 0; j < 4; ++j)
        if (j < w) prefix += wtot[j];
    x += prefix;
    if (i < NN) cscan[i] = x;
    if (tid == 255) bsum[blockIdx.x] = x;
}

__global__ __launch_bounds__(256) void scanB_k(const int* __restrict__ bsum,
                                               int* __restrict__ boff) {
    __shared__ int wtot[4];
    int tid = threadIdx.x, lane = tid & 63, w = tid >> 6;
    int v = (tid < NB) ? bsum[tid] : 0;
    int x = v;
#pragma unroll
    for (int off = 1; off < 64; off <<= 1) {
        int y = __shfl_up(x, off);
        if (lane >= off) x += y;
    }
    if (lane == 63) wtot[w] = x;
    __syncthreads();
    int prefix = 0;
#pragma unroll
    for (int j = 0; j < 4; ++j)
        if (j < w) prefix += wtot[j];
    x += prefix;
    if (tid < NB) boff[tid] = x - v;
    if (tid == NB - 1) boff[NB] = x;
}

__global__ __launch_bounds__(256) void scanC_k(const int* __restrict__ deg,
                                               const int* __restrict__ cscan,
                                               const int* __restrict__ boff,
                                               int* __restrict__ row_ptr,
                                               int* __restrict__ cursor) {
    int i = blockIdx.x * 256 + threadIdx.x;
    if (i < NN) {
        int e = boff[i >> 8] + cscan[i] - deg[i];
        row_ptr[i] = e;
        cursor[i] = e;
    }
    if (i == 0) row_ptr[NN] = boff[NB];
}

__global__ void scatter_k(const int* __restrict__ src, const int* __restrict__ dst,
                          int* __restrict__ cursor, int* __restrict__ csr_src) {
    int i = blockIdx.x * 256 + threadIdx.x;
    if (i < EE) {
        int slot = atomicAdd(&cursor[dst[i]], 1);
        csr_src[slot] = src[i];
    }
}

// ---------------- weights -> bf16 ----------------
__global__ __launch_bounds__(256) void bconv_k(const float* __restrict__ W2,
                                               const float* __restrict__ W3,
                                               const float* __restrict__ mW1,
                                               unsigned short* __restrict__ BT2,
                                               unsigned short* __restrict__ BT3,
                                               unsigned short* __restrict__ W1Tb) {
    int tid = blockIdx.x * 256 + threadIdx.x;   // 65536
    int k = tid & 255, n = tid >> 8;
    BT2[n * 256 + k] = f2bf(W2[k * 256 + n]);
    BT3[n * 256 + k] = f2bf(W3[k * 256 + n]);
    if (tid < 4096) {
        int kk = tid & 63, nn = tid >> 6;
        W1Tb[nn * 64 + kk] = f2bf(mW1[kk * 64 + nn]);
    }
}

// ---------------- layer-1 attention logits (pos-based) ----------------
__global__ __launch_bounds__(256) void eler1_k(const float* __restrict__ pos,
                                               const float* __restrict__ W1,
                                               const float* __restrict__ al,
                                               const float* __restrict__ ar,
                                               float* __restrict__ el,
                                               float* __restrict__ er) {
    int wid = blockIdx.x * 4 + (threadIdx.x >> 6);
    int lane = threadIdx.x & 63;
    if (wid >= NN) return;
    int f = lane * 4;
    float4 w0 = *(const float4*)&W1[f];
    float4 w1 = *(const float4*)&W1[256 + f];
    float4 a4 = *(const float4*)&al[f];
    float4 r4 = *(const float4*)&ar[f];
    float2 p = *(const float2*)&pos[wid * 2];
    float fx = p.x * w0.x + p.y * w1.x;
    float fy = p.x * w0.y + p.y * w1.y;
    float fz = p.x * w0.z + p.y * w1.z;
    float fw = p.x * w0.w + p.y * w1.w;
    float pl = fx * a4.x + fy * a4.y + fz * a4.z + fw * a4.w;
    float pr = fx * r4.x + fy * r4.y + fz * r4.z + fw * r4.w;
#pragma unroll
    for (int off = 1; off < 16; off <<= 1) {
        pl += __shfl_xor(pl, off);
        pr += __shfl_xor(pr, off);
    }
    if ((lane & 15) == 0) {
        int h = lane >> 4;
        el[wid * 4 + h] = pl;
        er[wid * 4 + h] = pr;
    }
}

// ---------------- layer-1 aggregation: wave-parallel edges (16 lanes per head) ----------------
__global__ __launch_bounds__(256) void agg1_k(const float* __restrict__ pos,
                                              const float* __restrict__ W1,
                                              const float* __restrict__ resW1,
                                              const float* __restrict__ el,
                                              const float* __restrict__ er,
                                              const int* __restrict__ row_ptr,
                                              const int* __restrict__ csr_src,
                                              unsigned short* __restrict__ hb16) {
    int wid = blockIdx.x * 4 + (threadIdx.x >> 6);
    int lane = threadIdx.x & 63;
    if (wid >= NN) return;
    int f = lane * 4;
    int start = row_ptr[wid], end = row_ptr[wid + 1];
    int h = lane >> 4, sub = lane & 15;
    float eh = er[wid * 4 + h];

    float ap0 = 0.f, ap1 = 0.f, den = 0.f;
    for (int s = start + sub; s < end; s += 16) {
        int sn = csr_src[s];
        float w = __expf(lrelu(el[sn * 4 + h] + eh));
        float2 p = *(const float2*)&pos[sn * 2];
        den += w;
        ap0 += w * p.x;
        ap1 += w * p.y;
    }
#pragma unroll
    for (int off = 1; off < 16; off <<= 1) {
        den += __shfl_xor(den, off);
        ap0 += __shfl_xor(ap0, off);
        ap1 += __shfl_xor(ap1, off);
    }
    float inv = 1.f / fmaxf(den, 1e-9f);
    ap0 *= inv;
    ap1 *= inv;

    float4 w0 = *(const float4*)&W1[f];
    float4 w1 = *(const float4*)&W1[256 + f];
    float4 rw0 = *(const float4*)&resW1[f];
    float4 rw1 = *(const float4*)&resW1[256 + f];
    float2 pd = *(const float2*)&pos[wid * 2];
    float4 o;
    o.x = fmaxf(ap0 * w0.x + ap1 * w1.x + pd.x * rw0.x + pd.y * rw1.x, 0.f);
    o.y = fmaxf(ap0 * w0.y + ap1 * w1.y + pd.x * rw0.y + pd.y * rw1.y, 0.f);
    o.z = fmaxf(ap0 * w0.z + ap1 * w1.z + pd.x * rw0.z + pd.y * rw1.z, 0.f);
    o.w = fmaxf(ap0 * w0.w + ap1 * w1.w + pd.x * rw0.w + pd.y * rw1.w, 0.f);
    ushort4 ob;
    ob.x = f2bf(o.x); ob.y = f2bf(o.y); ob.z = f2bf(o.z); ob.w = f2bf(o.w);
    *(ushort4*)&hb16[(size_t)wid * 256 + f] = ob;
}

// ---------------- layer-2 aggregation: one-pass softmax, unroll-4 ----------------
__global__ __launch_bounds__(256) void agg_k(const unsigned short* __restrict__ featb,
                                             const float* __restrict__ el,
                                             const float* __restrict__ er,
                                             const int* __restrict__ row_ptr,
                                             const int* __restrict__ csr_src,
                                             unsigned short* __restrict__ hb16) {
    int wid = blockIdx.x * 4 + (threadIdx.x >> 6);
    int lane = threadIdx.x & 63;
    if (wid >= NN) return;
    int f = lane * 4;
    int start = row_ptr[wid], end = row_ptr[wid + 1];
    int h = lane >> 4;
    float eh = er[wid * 4 + h];

    float4 acc = {0.f, 0.f, 0.f, 0.f};
    float den = 0.f;
    int s = start;
    for (; s + 3 < end; s += 4) {
        int sn0 = csr_src[s], sn1 = csr_src[s + 1];
        int sn2 = csr_src[s + 2], sn3 = csr_src[s + 3];
        float e0 = el[sn0 * 4 + h], e1 = el[sn1 * 4 + h];
        float e2 = el[sn2 * 4 + h], e3 = el[sn3 * 4 + h];
        ushort4 v0 = *(const ushort4*)&featb[(size_t)sn0 * 256 + f];
        ushort4 v1 = *(const ushort4*)&featb[(size_t)sn1 * 256 + f];
        ushort4 v2 = *(const ushort4*)&featb[(size_t)sn2 * 256 + f];
        ushort4 v3 = *(const ushort4*)&featb[(size_t)sn3 * 256 + f];
        float w0 = __expf(lrelu(e0 + eh)), w1 = __expf(lrelu(e1 + eh));
        float w2 = __expf(lrelu(e2 + eh)), w3 = __expf(lrelu(e3 + eh));
        den += (w0 + w1) + (w2 + w3);
        acc.x += w0 * bf2f(v0.x) + w1 * bf2f(v1.x) + w2 * bf2f(v2.x) + w3 * bf2f(v3.x);
        acc.y += w0 * bf2f(v0.y) + w1 * bf2f(v1.y) + w2 * bf2f(v2.y) + w3 * bf2f(v3.y);
        acc.z += w0 * bf2f(v0.z) + w1 * bf2f(v1.z) + w2 * bf2f(v2.z) + w3 * bf2f(v3.z);
        acc.w += w0 * bf2f(v0.w) + w1 * bf2f(v1.w) + w2 * bf2f(v2.w) + w3 * bf2f(v3.w);
    }
    for (; s < end; ++s) {
        int sn = csr_src[s];
        float w = __expf(lrelu(el[sn * 4 + h] + eh));
        ushort4 v = *(const ushort4*)&featb[(size_t)sn * 256 + f];
        den += w;
        acc.x += w * bf2f(v.x);
        acc.y += w * bf2f(v.y);
        acc.z += w * bf2f(v.z);
        acc.w += w * bf2f(v.w);
    }
    float inv = 1.f / fmaxf(den, 1e-9f);
    ushort4 rb = *(const ushort4*)&hb16[(size_t)wid * 256 + f];
    float4 o;
    o.x = fmaxf(acc.x * inv + bf2f(rb.x), 0.f);
    o.y = fmaxf(acc.y * inv + bf2f(rb.y), 0.f);
    o.z = fmaxf(acc.z * inv + bf2f(rb.z), 0.f);
    o.w = fmaxf(acc.w * inv + bf2f(rb.w), 0.f);
    ushort4 ob;
    ob.x = f2bf(o.x); ob.y = f2bf(o.y); ob.z = f2bf(o.z); ob.w = f2bf(o.w);
    *(ushort4*)&hb16[(size_t)wid * 256 + f] = ob;
}

// ---------------- layer-3 aggregation, mean over heads -> bf16 hsmall ----------------
__global__ __launch_bounds__(256) void agg3_k(const unsigned short* __restrict__ featb,
                                              const float* __restrict__ el,
                                              const float* __restrict__ er,
                                              const int* __restrict__ row_ptr,
                                              const int* __restrict__ csr_src,
                                              const unsigned short* __restrict__ hresb,
                                              unsigned short* __restrict__ hsmallb) {
    int wid = blockIdx.x * 4 + (threadIdx.x >> 6);
    int lane = threadIdx.x & 63;
    if (wid >= NN) return;
    int f = lane * 4;
    int start = row_ptr[wid], end = row_ptr[wid + 1];
    int h = lane >> 4;
    float eh = er[wid * 4 + h];

    float4 acc = {0.f, 0.f, 0.f, 0.f};
    float den = 0.f;
    int s = start;
    for (; s + 3 < end; s += 4) {
        int sn0 = csr_src[s], sn1 = csr_src[s + 1];
        int sn2 = csr_src[s + 2], sn3 = csr_src[s + 3];
        float e0 = el[sn0 * 4 + h], e1 = el[sn1 * 4 + h];
        float e2 = el[sn2 * 4 + h], e3 = el[sn3 * 4 + h];
        ushort4 v0 = *(const ushort4*)&featb[(size_t)sn0 * 256 + f];
        ushort4 v1 = *(const ushort4*)&featb[(size_t)sn1 * 256 + f];
        ushort4 v2 = *(const ushort4*)&featb[(size_t)sn2 * 256 + f];
        ushort4 v3 = *(const ushort4*)&featb[(size_t)sn3 * 256 + f];
        float w0 = __expf(lrelu(e0 + eh)), w1 = __expf(lrelu(e1 + eh));
        float w2 = __expf(lrelu(e2 + eh)), w3 = __expf(lrelu(e3 + eh));
        den += (w0 + w1) + (w2 + w3);
        acc.x += w0 * bf2f(v0.x) + w1 * bf2f(v1.x) + w2 * bf2f(v2.x) + w3 * bf2f(v3.x);
        acc.y += w0 * bf2f(v0.y) + w1 * bf2f(v1.y) + w2 * bf2f(v2.y) + w3 * bf2f(v3.y);
        acc.z += w0 * bf2f(v0.z) + w1 * bf2f(v1.z) + w2 * bf2f(v2.z) + w3 * bf2f(v3.z);
        acc.w += w0 * bf2f(v0.w) + w1 * bf2f(v1.w) + w2 * bf2f(v2.w) + w3 * bf2f(v3.w);
    }
    for (; s < end; ++s) {
        int sn = csr_src[s];
        float w = __expf(lrelu(el[sn * 4 + h] + eh));
        ushort4 v = *(const ushort4*)&featb[(size_t)sn * 256 + f];
        den += w;
        acc.x += w * bf2f(v.x);
        acc.y += w * bf2f(v.y);
        acc.z += w * bf2f(v.z);
        acc.w += w * bf2f(v.w);
    }
    float inv = 1.f / fmaxf(den, 1e-9f);
    ushort4 rb = *(const ushort4*)&hresb[(size_t)wid * 256 + f];
    float4 o;
    o.x = acc.x * inv + bf2f(rb.x);
    o.y = acc.y * inv + bf2f(rb.y);
    o.z = acc.z * inv + bf2f(rb.z);
    o.w = acc.w * inv + bf2f(rb.w);
    o.x += __shfl_xor(o.x, 16); o.y += __shfl_xor(o.y, 16);
    o.z += __shfl_xor(o.z, 16); o.w += __shfl_xor(o.w, 16);
    o.x += __shfl_xor(o.x, 32); o.y += __shfl_xor(o.y, 32);
    o.z += __shfl_xor(o.z, 32); o.w += __shfl_xor(o.w, 32);
    if (lane < 16) {
        ushort4 m4;
        m4.x = f2bf(o.x * 0.25f);
        m4.y = f2bf(o.y * 0.25f);
        m4.z = f2bf(o.z * 0.25f);
        m4.w = f2bf(o.w * 0.25f);
        *(ushort4*)&hsmallb[(size_t)wid * 64 + lane * 4] = m4;
    }
}

// ---------------- MFMA GEMM (LDS-staged) + fused el/er epilogue ----------------
__global__ __launch_bounds__(256) void gemm_mfma_k(const unsigned short* __restrict__ Ab,
                                                   const unsigned short* __restrict__ BT,
                                                   const float* __restrict__ al,
                                                   const float* __restrict__ ar,
                                                   unsigned short* __restrict__ C,
                                                   float* __restrict__ el,
                                                   float* __restrict__ er) {
    __shared__ __align__(16) short As[128 * 40];
    __shared__ __align__(16) short Bs[128 * 40];
    int tid = threadIdx.x;
    int lane = tid & 63, wave = tid >> 6;
    int wr = wave >> 1, wc = wave & 1;
    int tileM = blockIdx.x * 128;
    int tileN = blockIdx.y * 128;

    int srow = tid >> 1, sko = (tid & 1) * 16;
    int fm = lane & 15, kg = lane >> 4;

    f32x4 acc[4][4];
#pragma unroll
    for (int i = 0; i < 4; ++i)
#pragma unroll
        for (int j = 0; j < 4; ++j) acc[i][j] = (f32x4){0.f, 0.f, 0.f, 0.f};

    for (int k0 = 0; k0 < 256; k0 += 32) {
        int gr = tileM + srow;
        short8 a0 = (short8)0, a1 = (short8)0;
        if (gr < NN) {
            a0 = *(const short8*)&Ab[(size_t)gr * 256 + k0 + sko];
            a1 = *(const short8*)&Ab[(size_t)gr * 256 + k0 + sko + 8];
        }
        *(short8*)&As[srow * 40 + sko] = a0;
        *(short8*)&As[srow * 40 + sko + 8] = a1;
        short8 b0 = *(const short8*)&BT[(size_t)(tileN + srow) * 256 + k0 + sko];
        short8 b1 = *(const short8*)&BT[(size_t)(tileN + srow) * 256 + k0 + sko + 8];
        *(short8*)&Bs[srow * 40 + sko] = b0;
        *(short8*)&Bs[srow * 40 + sko + 8] = b1;
        __syncthreads();

        short8 afr[4], bfr[4];
#pragma unroll
        for (int mi = 0; mi < 4; ++mi)
            afr[mi] = *(const short8*)&As[(wr * 64 + mi * 16 + fm) * 40 + kg * 8];
#pragma unroll
        for (int ni = 0; ni < 4; ++ni)
            bfr[ni] = *(const short8*)&Bs[(wc * 64 + ni * 16 + fm) * 40 + kg * 8];
#pragma unroll
        for (int mi = 0; mi < 4; ++mi)
#pragma unroll
            for (int ni = 0; ni < 4; ++ni)
                acc[mi][ni] = __builtin_amdgcn_mfma_f32_16x16x32_bf16(
                    afr[mi], bfr[ni], acc[mi][ni], 0, 0, 0);
        __syncthreads();
    }

#pragma unroll
    for (int mi = 0; mi < 4; ++mi) {
#pragma unroll
        for (int ni = 0; ni < 4; ++ni) {
            int col = tileN + wc * 64 + ni * 16 + fm;
#pragma unroll
            for (int r = 0; r < 4; ++r) {
                int row = tileM + wr * 64 + mi * 16 + kg * 4 + r;
                if (row < NN) C[(size_t)row * 256 + col] = f2bf(acc[mi][ni][r]);
            }
        }
    }

    int h = blockIdx.y * 2 + wc;
    float al_r[4], ar_r[4];
#pragma unroll
    for (int ni = 0; ni < 4; ++ni) {
        al_r[ni] = al[h * 64 + ni * 16 + fm];
        ar_r[ni] = ar[h * 64 + ni * 16 + fm];
    }
#pragma unroll
    for (int mi = 0; mi < 4; ++mi) {
#pragma unroll
        for (int r = 0; r < 4; ++r) {
            float tl = acc[mi][0][r] * al_r[0] + acc[mi][1][r] * al_r[1] +
                       acc[mi][2][r] * al_r[2] + acc[mi][3][r] * al_r[3];
            float tr = acc[mi][0][r] * ar_r[0] + acc[mi][1][r] * ar_r[1] +
                       acc[mi][2][r] * ar_r[2] + acc[mi][3][r] * ar_r[3];
#pragma unroll
            for (int off = 1; off < 16; off <<= 1) {
                tl += __shfl_xor(tl, off);
                tr += __shfl_xor(tr, off);
            }
            if (fm == 0) {
                int row = tileM + wr * 64 + mi * 16 + kg * 4 + r;
                if (row < NN) {
                    el[row * 4 + h] = tl;
                    er[row * 4 + h] = tr;
                }
            }
        }
    }
}

// ---------------- edge scoring MLP: MFMA, 64 edges/block, wt staged in LDS ----------------
__global__ __launch_bounds__(256) void edge_score4_k(const unsigned short* __restrict__ hs,
                                                     const int* __restrict__ src,
                                                     const int* __restrict__ dst,
                                                     const unsigned short* __restrict__ W1Tb,
                                                     const float* __restrict__ mb1,
                                                     const float* __restrict__ mW2,
                                                     const float* __restrict__ mb2,
                                                     float* __restrict__ out) {
    __shared__ __align__(16) unsigned short xs[64 * 72];
    __shared__ __align__(16) unsigned short wt[64 * 72];
    __shared__ float b1s[64], w2s[64];
    int tid = threadIdx.x;
    int e_loc = tid >> 2, q = tid & 3;

    *(short8*)&wt[e_loc * 72 + q * 16]     = *(const short8*)&W1Tb[e_loc * 64 + q * 16];
    *(short8*)&wt[e_loc * 72 + q * 16 + 8] = *(const short8*)&W1Tb[e_loc * 64 + q * 16 + 8];
    if (tid < 64) { b1s[tid] = mb1[tid]; w2s[tid] = mW2[tid]; }

    int e = blockIdx.x * 64 + e_loc;                 // EE % 64 == 0
    int s = src[e], d = dst[e];
    const unsigned short* rs = &hs[(size_t)s * 64 + q * 16];
    const unsigned short* rd = &hs[(size_t)d * 64 + q * 16];
    short8 a0 = *(const short8*)&rs[0];
    short8 a1 = *(const short8*)&rs[8];
    short8 b0 = *(const short8*)&rd[0];
    short8 b1 = *(const short8*)&rd[8];
    short8 x0, x1;
#pragma unroll
    for (int i = 0; i < 8; ++i) {
        x0[i] = (short)f2bf(fabsf(bf2f((unsigned short)a0[i]) - bf2f((unsigned short)b0[i])));
        x1[i] = (short)f2bf(fabsf(bf2f((unsigned short)a1[i]) - bf2f((unsigned short)b1[i])));
    }
    *(short8*)&xs[e_loc * 72 + q * 16]     = x0;
    *(short8*)&xs[e_loc * 72 + q * 16 + 8] = x1;
    __syncthreads();

    int lane = tid & 63, w = tid >> 6;
    int fm = lane & 15, kg = lane >> 4;

    const unsigned short* arow = &xs[(w * 16 + fm) * 72];
    short8 af0 = *(const short8*)&arow[kg * 8];
    short8 af1 = *(const short8*)&arow[32 + kg * 8];

    f32x4 acc[4];
#pragma unroll
    for (int ni = 0; ni < 4; ++ni) acc[ni] = (f32x4){0.f, 0.f, 0.f, 0.f};
#pragma unroll
    for (int ni = 0; ni < 4; ++ni) {
        const unsigned short* brow = &wt[(ni * 16 + fm) * 72];
        short8 bf0 = *(const short8*)&brow[kg * 8];
        short8 bf1 = *(const short8*)&brow[32 + kg * 8];
        acc[ni] = __builtin_amdgcn_mfma_f32_16x16x32_bf16(af0, bf0, acc[ni], 0, 0, 0);
        acc[ni] = __builtin_amdgcn_mfma_f32_16x16x32_bf16(af1, bf1, acc[ni], 0, 0, 0);
    }

    float t0 = 0.f, t1 = 0.f, t2 = 0.f, t3 = 0.f;
#pragma unroll
    for (int ni = 0; ni < 4; ++ni) {
        int n = ni * 16 + fm;
        float bb = b1s[n], ww = w2s[n];
        t0 += fmaxf(acc[ni][0] + bb, 0.f) * ww;
        t1 += fmaxf(acc[ni][1] + bb, 0.f) * ww;
        t2 += fmaxf(acc[ni][2] + bb, 0.f) * ww;
        t3 += fmaxf(acc[ni][3] + bb, 0.f) * ww;
    }
#pragma unroll
    for (int off = 1; off < 16; off <<= 1) {
        t0 += __shfl_xor(t0, off);
        t1 += __shfl_xor(t1, off);
        t2 += __shfl_xor(t2, off);
        t3 += __shfl_xor(t3, off);
    }
    if (fm == 0) {
        float bias = mb2[0];
        int base = blockIdx.x * 64 + w * 16 + kg * 4;
        out[base + 0] = 1.f / (1.f + __expf(-(t0 + bias)));
        out[base + 1] = 1.f / (1.f + __expf(-(t1 + bias)));
        out[base + 2] = 1.f / (1.f + __expf(-(t2 + bias)));
        out[base + 3] = 1.f / (1.f + __expf(-(t3 + bias)));
    }
}

extern "C" void kernel_launch(void* const* d_in, const int* in_sizes, int n_in,
                              void* d_out, int out_size, void* d_ws, size_t ws_size,
                              hipStream_t stream) {
    (void)in_sizes; (void)n_in; (void)out_size; (void)ws_size;
    const float* pos   = (const float*)d_in[0];
    const int*   src   = (const int*)d_in[1];
    const int*   dst   = (const int*)d_in[2];
    const float* W1    = (const float*)d_in[3];
    const float* al1   = (const float*)d_in[4];
    const float* ar1   = (const float*)d_in[5];
    const float* resW1 = (const float*)d_in[6];
    const float* W2    = (const float*)d_in[7];
    const float* al2   = (const float*)d_in[8];
    const float* ar2   = (const float*)d_in[9];
    const float* W3    = (const float*)d_in[10];
    const float* al3   = (const float*)d_in[11];
    const float* ar3   = (const float*)d_in[12];
    const float* mW1   = (const float*)d_in[13];
    const float* mb1   = (const float*)d_in[14];
    const float* mW2   = (const float*)d_in[15];
    const float* mb2   = (const float*)d_in[16];
    float* out = (float*)d_out;

    char* ws = (char*)d_ws;
    size_t off = 0;
    auto alloc = [&](size_t bytes) {
        void* p = ws + off;
        off += (bytes + 255) & ~(size_t)255;
        return p;
    };
    unsigned short* FEATb  = (unsigned short*)alloc((size_t)NN * 256 * 2);
    unsigned short* Hb16   = (unsigned short*)alloc((size_t)NN * 256 * 2);
    unsigned short* BT2    = (unsigned short*)alloc((size_t)256 * 256 * 2);
    unsigned short* BT3    = (unsigned short*)alloc((size_t)256 * 256 * 2);
    unsigned short* W1Tb   = (unsigned short*)alloc((size_t)64 * 64 * 2);
    unsigned short* hsmallb = (unsigned short*)alloc((size_t)NN * 64 * 2);
    float* el     = (float*)alloc((size_t)NN * 4 * 4);
    float* er     = (float*)alloc((size_t)NN * 4 * 4);
    int* deg      = (int*)alloc((size_t)NN * 4);
    int* cscan    = (int*)alloc((size_t)NN * 4);
    int* bsum     = (int*)alloc((size_t)NB * 4);
    int* boff     = (int*)alloc((size_t)(NB + 1) * 4);
    int* row_ptr  = (int*)alloc((size_t)(NN + 1) * 4);
    int* cursor   = (int*)alloc((size_t)NN * 4);
    int* csr      = (int*)alloc((size_t)EE * 4);

    hipMemsetAsync(deg, 0, (size_t)NN * 4, stream);
    hist_k<<<(EE + 255) / 256, 256, 0, stream>>>(dst, deg);
    scanA_k<<<NB, 256, 0, stream>>>(deg, cscan, bsum);
    scanB_k<<<1, 256, 0, stream>>>(bsum, boff);
    scanC_k<<<NB, 256, 0, stream>>>(deg, cscan, boff, row_ptr, cursor);
    scatter_k<<<(EE + 255) / 256, 256, 0, stream>>>(src, dst, cursor, csr);
    bconv_k<<<256, 256, 0, stream>>>(W2, W3, mW1, BT2, BT3, W1Tb);

    // layer 1
    eler1_k<<<NN / 4 + 1, 256, 0, stream>>>(pos, W1, al1, ar1, el, er);
    agg1_k<<<NN / 4 + 1, 256, 0, stream>>>(pos, W1, resW1, el, er, row_ptr, csr, Hb16);

    dim3 ggrid((NN + 127) / 128, 2);
    // layer 2 (gemm computes FEATb + el/er in one pass)
    gemm_mfma_k<<<ggrid, 256, 0, stream>>>(Hb16, BT2, al2, ar2, FEATb, el, er);
    agg_k<<<NN / 4 + 1, 256, 0, stream>>>(FEATb, el, er, row_ptr, csr, Hb16);

    // layer 3
    gemm_mfma_k<<<ggrid, 256, 0, stream>>>(Hb16, BT3, al3, ar3, FEATb, el, er);
    agg3_k<<<NN / 4 + 1, 256, 0, stream>>>(FEATb, el, er, row_ptr, csr, Hb16, hsmallb);

    // edge MLP (MFMA)
    edge_score4_k<<<EE / 64, 256, 0, stream>>>(hsmallb, src, dst, W1Tb, mb1, mW2, mb2, out);
}